// Round 6
// baseline (574.824 us; speedup 1.0000x reference)
//
#include <hip/hip_runtime.h>
#include <math.h>

// DualStreamBlock: B=4, DIM=96, DIM3=288, H=W=64, L=4096, DSTATE=16
// di=192, di3=576, r=6, r3=18
#define L 4096

typedef unsigned short u16;
typedef float f32x4 __attribute__((ext_vector_type(4)));
typedef short s16x8 __attribute__((ext_vector_type(8)));
typedef __attribute__((address_space(3))) unsigned int lds_u32;
typedef __attribute__((address_space(1))) unsigned int glb_u32;

__device__ __forceinline__ float softplus_f(float x) {
  return fmaxf(x, 0.f) + log1pf(__expf(-fabsf(x)));
}
__device__ __forceinline__ float silu_f(float x) {
  return x / (1.f + __expf(-x));
}
__device__ __forceinline__ float bf2f(u16 v) {
  return __uint_as_float(((unsigned)v) << 16);
}
__device__ __forceinline__ u16 f2bf(float f) {
  unsigned u = __float_as_uint(f);
  u += 0x7FFFu + ((u >> 16) & 1u);
  return (u16)(u >> 16);
}

// ---------------------------------------------------------------------------
// Weight convert: fp32 W[K][N] -> bf16 Wt[Npad][K] (transposed, zero-padded)
// ---------------------------------------------------------------------------
struct WSeg { const float* src; u16* dst; int K, N, Npad; };
struct WAll { WSeg s[9]; };

__global__ __launch_bounds__(256) void wconv_k(WAll wa) {
  const WSeg w = wa.s[blockIdx.z];
  const int nb = blockIdx.x * 32, kb = blockIdx.y * 32;
  if (nb >= w.Npad || kb >= w.K) return;
  __shared__ float t[32][33];
  const int tx = threadIdx.x & 31, ty = threadIdx.x >> 5;
  for (int r = ty; r < 32; r += 8) {
    int k = kb + r, n = nb + tx;
    t[r][tx] = (n < w.N) ? w.src[(size_t)k * w.N + n] : 0.f;
  }
  __syncthreads();
  for (int r = ty; r < 32; r += 8) {
    int n = nb + r;
    w.dst[(size_t)n * w.K + kb + tx] = f2bf(t[tx][r]);
  }
}

// ---------------------------------------------------------------------------
// Tiled transpose prep: chan-major fp32 (B,C,L) -> token-major bf16 [B*L][C]
// DO_LN=1: LayerNorm over C (gamma/beta). DO_LN=0: optional +bias2[b*C+c].
// ---------------------------------------------------------------------------
template<int DO_LN>
__global__ __launch_bounds__(256) void trans_bf_k(
    const float* __restrict__ x, const float* __restrict__ gam,
    const float* __restrict__ bet, const float* __restrict__ bias2,
    u16* __restrict__ out, int C) {
  __shared__ float tile[288][33];
  __shared__ float psum[8][32], psq[8][32];
  __shared__ float mm[32], rr[32];
  const int tid = threadIdx.x;
  const int l0 = blockIdx.x * 32;
  const int b = blockIdx.y;
  const int lane32 = tid & 31, row8 = tid >> 5;
  const float* xb = x + (size_t)b * C * L + l0;

  for (int c = row8; c < C; c += 8)
    tile[c][lane32] = xb[(size_t)c * L + lane32];
  __syncthreads();

  if (DO_LN) {
    float s = 0.f, sq = 0.f;
    for (int c = row8; c < C; c += 8) {
      float v = tile[c][lane32];
      s += v; sq = fmaf(v, v, sq);
    }
    psum[row8][lane32] = s; psq[row8][lane32] = sq;
    __syncthreads();
    if (row8 == 0) {
      float ts = 0.f, tq = 0.f;
      #pragma unroll
      for (int g = 0; g < 8; ++g) { ts += psum[g][lane32]; tq += psq[g][lane32]; }
      float m = ts / C;
      float var = tq / C - m * m;
      mm[lane32] = m;
      rr[lane32] = rsqrtf(var + 1e-5f);
    }
    __syncthreads();
  }

  u16* ob = out + ((size_t)b * L + l0) * C;
  const int total = 32 * C;
  for (int o = tid * 8; o < total; o += 2048) {
    int t = o / C, c = o % C;
    float m = 0.f, rs = 0.f;
    if (DO_LN) { m = mm[t]; rs = rr[t]; }
    union { u16 u[8]; int4 v; } pk;
    #pragma unroll
    for (int j = 0; j < 8; ++j) {
      float v = tile[c + j][t];
      if (DO_LN) v = (v - m) * rs * gam[c + j] + bet[c + j];
      else if (bias2) v += bias2[b * C + c + j];
      pk.u[j] = f2bf(v);
    }
    *(int4*)(ob + o) = pk.v;
  }
}

// ---------------------------------------------------------------------------
// causal depthwise conv k=4 + bias + silu, token-major bf16 in/out
// ---------------------------------------------------------------------------
__global__ __launch_bounds__(256) void conv_bf_k(const u16* __restrict__ x,
    const float* __restrict__ w, const float* __restrict__ bias,
    u16* __restrict__ y, int C) {
  const int c = blockIdx.x * 64 + (threadIdx.x & 63);
  const int chunk = blockIdx.y * 4 + (threadIdx.x >> 6);
  const int T0 = chunk * 8;
  const float w0 = w[c * 4], w1 = w[c * 4 + 1], w2 = w[c * 4 + 2], w3 = w[c * 4 + 3];
  const float bs = bias[c];
  const bool first = (T0 & (L - 1)) == 0;
  float v[11];
  #pragma unroll
  for (int i = 0; i < 11; ++i) {
    if (i < 3 && first) v[i] = 0.f;
    else v[i] = bf2f(x[(size_t)(T0 - 3 + i) * C + c]);
  }
  #pragma unroll
  for (int j = 0; j < 8; ++j) {
    float s = bs + w0 * v[j] + w1 * v[j + 1] + w2 * v[j + 2] + w3 * v[j + 3];
    y[(size_t)(T0 + j) * C + c] = f2bf(silu_f(s));
  }
}

// ---------------------------------------------------------------------------
// MFMA bf16 GEMM: A [M=16384][K] token-major bf16 (optional concat A0|A1),
// Wt [Npad][K] bf16. Tile 128x128, 4 waves (2x2), BK=32.
// Depth-2 counted-vmcnt pipeline: 3 LDS stages; vmcnt(8) in steady state
// (stages t+1, t+2 stay in flight across raw s_barrier); drains 8->4->0.
// 1-D grid, XCD-bijective swizzle, m-major chunking (A-strip stays on 1 XCD).
// EPI: 0 fp32 row-major; 1 bf16 row-major; 2 chan-major fp32 + residual;
//      3 silu(x+bias) bf16; 4 (x+bias) bf16; 5 split bf16 (out0|out1).
// ---------------------------------------------------------------------------
struct MP {
  const u16 *A0, *A1, *Wt;
  const float *bias, *res;
  float* outF; u16 *outB0, *outB1;
  int K, K1, Nout, ldA, ldo, split, nbx;
};

template<int EPI>
__global__ __launch_bounds__(256) void mfma_gemm_k(MP p) {
  __shared__ u16 As[3][4096];
  __shared__ u16 Bs[3][4096];
  const int tid = threadIdx.x;
  const int lane = tid & 63;
  const int wid = tid >> 6;
  const int wm = wid >> 1, wn = wid & 1;
  // XCD-bijective swizzle (all grids here are multiples of 8; chunk%nbx==0)
  const int nwg = gridDim.x;
  const int wg = blockIdx.x;
  const int newid = (wg & 7) * (nwg >> 3) + (wg >> 3);
  const int n0 = (newid % p.nbx) * 128;
  const int m0 = (newid / p.nbx) * 128;
  const int srow = tid & 127;
  const int skc = tid >> 7;
  const int kgrp = lane >> 4, l16 = lane & 15;

  f32x4 acc[4][4];
  #pragma unroll
  for (int i = 0; i < 4; ++i)
    #pragma unroll
    for (int j = 0; j < 4; ++j)
      acc[i][j] = (f32x4){0.f, 0.f, 0.f, 0.f};

  auto stage = [&](int bi, int t) {
    const int k0 = t << 5;
    const u16* Ab = p.A0;
    int kc = k0;
    if (p.A1 && k0 >= p.K1) { Ab = p.A1; kc = k0 - p.K1; }
    const u16* g0 = Ab + (size_t)(m0 + srow) * p.ldA + kc + skc * 8;
    u16* Ad = &As[bi][0];
    __builtin_amdgcn_global_load_lds((const glb_u32*)g0,
        (lds_u32*)(Ad + wid * 512), 16, 0, 0);
    __builtin_amdgcn_global_load_lds((const glb_u32*)(g0 + 16),
        (lds_u32*)(Ad + 2048 + wid * 512), 16, 0, 0);
    const u16* h0 = p.Wt + (size_t)(n0 + srow) * p.K + k0 + skc * 8;
    u16* Bd = &Bs[bi][0];
    __builtin_amdgcn_global_load_lds((const glb_u32*)h0,
        (lds_u32*)(Bd + wid * 512), 16, 0, 0);
    __builtin_amdgcn_global_load_lds((const glb_u32*)(h0 + 16),
        (lds_u32*)(Bd + 2048 + wid * 512), 16, 0, 0);
  };

  const int nt = p.K >> 5;   // all our K are >= 96 -> nt >= 3
  stage(0, 0);
  stage(1, 1);
  for (int t = 0; t < nt; ++t) {
    const int cur = t % 3;
    if (t + 2 < nt) stage((t + 2) % 3, t + 2);
    // wait until this wave's stage-t loads have landed (counted, never 0 mid-loop)
    if (t + 2 < nt)      asm volatile("s_waitcnt vmcnt(8)" ::: "memory");
    else if (t + 1 < nt) asm volatile("s_waitcnt vmcnt(4)" ::: "memory");
    else                 asm volatile("s_waitcnt vmcnt(0)" ::: "memory");
    __builtin_amdgcn_s_barrier();           // all waves' stage-t portions present
    __builtin_amdgcn_sched_barrier(0);      // forbid hoisting LDS reads above barrier
    s16x8 af[4], bfr[4];
    #pragma unroll
    for (int mi = 0; mi < 4; ++mi)
      af[mi] = *(const s16x8*)(&As[cur][0] + kgrp * 1024 + (wm * 64 + mi * 16 + l16) * 8);
    #pragma unroll
    for (int ni = 0; ni < 4; ++ni)
      bfr[ni] = *(const s16x8*)(&Bs[cur][0] + kgrp * 1024 + (wn * 64 + ni * 16 + l16) * 8);
    #pragma unroll
    for (int mi = 0; mi < 4; ++mi)
      #pragma unroll
      for (int ni = 0; ni < 4; ++ni)
        acc[mi][ni] = __builtin_amdgcn_mfma_f32_16x16x32_bf16(af[mi], bfr[ni], acc[mi][ni], 0, 0, 0);
    __builtin_amdgcn_sched_barrier(0);      // forbid sinking LDS reads below barrier
    __builtin_amdgcn_s_barrier();           // protect ring buffer reuse
  }

  if (EPI == 2) {
    #pragma unroll
    for (int mi = 0; mi < 4; ++mi) {
      int token = m0 + wm * 64 + mi * 16 + (lane >> 4) * 4;
      int b = token >> 12, l = token & (L - 1);
      #pragma unroll
      for (int ni = 0; ni < 4; ++ni) {
        int n = n0 + wn * 64 + ni * 16 + l16;
        if (n < p.Nout) {
          size_t o = ((size_t)b * p.Nout + n) * L + l;
          float4 r = *(const float4*)(p.res + o);
          float4 v = make_float4(acc[mi][ni][0] + r.x, acc[mi][ni][1] + r.y,
                                 acc[mi][ni][2] + r.z, acc[mi][ni][3] + r.w);
          *(float4*)(p.outF + o) = v;
        }
      }
    }
  } else {
    #pragma unroll
    for (int mi = 0; mi < 4; ++mi) {
      #pragma unroll
      for (int j = 0; j < 4; ++j) {
        int token = m0 + wm * 64 + mi * 16 + (lane >> 4) * 4 + j;
        #pragma unroll
        for (int ni = 0; ni < 4; ++ni) {
          int n = n0 + wn * 64 + ni * 16 + l16;
          float v = acc[mi][ni][j];
          if (EPI == 0) {
            if (n < p.Nout) p.outF[(size_t)token * p.ldo + n] = v;
          } else if (EPI == 1) {
            if (n < p.Nout) p.outB0[(size_t)token * p.ldo + n] = f2bf(v);
          } else if (EPI == 3) {
            if (n < p.Nout) p.outB0[(size_t)token * p.ldo + n] = f2bf(silu_f(v + p.bias[n]));
          } else if (EPI == 4) {
            if (n < p.Nout) p.outB0[(size_t)token * p.ldo + n] = f2bf(v + p.bias[n]);
          } else {  // 5: split
            if (n < p.split) p.outB0[(size_t)token * p.split + n] = f2bf(v);
            else p.outB1[(size_t)token * p.split + (n - p.split)] = f2bf(v);
          }
        }
      }
    }
  }
}

// ---------------------------------------------------------------------------
// small fp32 GEMM (dt projection): A row-major [M][lda], W fp32 [K][N],
// EPI: softplus(x + ebias[n]) -> fp32 row-major [M][N]
// ---------------------------------------------------------------------------
struct GemmP {
  const float* A0; const float* W; const float* ebias;
  float* out0;
  int K, N, lda, ldo;
};

__global__ __launch_bounds__(256) void gemm_f32_k(GemmP p) {
  __shared__ __align__(16) float As[16][64];
  __shared__ __align__(16) float Bs[16][64];
  const int tid = threadIdx.x;
  const int kidx = tid >> 4;
  const int li4 = (tid & 15) << 2;
  const int r0 = (tid & 15) << 2;
  const int c0 = (tid >> 4) << 2;
  const int n0 = blockIdx.x * 64;
  const int m0 = blockIdx.y * 64;
  float acc[4][4] = {};

  for (int k0 = 0; k0 < p.K; k0 += 16) {
    __syncthreads();
    {
      const int row = tid >> 2;
      const int kk4 = (tid & 3) << 2;
      const float* src = p.A0 + (size_t)(m0 + row) * p.lda;
      #pragma unroll
      for (int j = 0; j < 4; ++j) {
        int k = k0 + kk4 + j;
        As[kk4 + j][row] = (k < p.K) ? src[k] : 0.f;
      }
    }
    {
      int k = k0 + kidx;
      #pragma unroll
      for (int j = 0; j < 4; ++j) {
        int n = n0 + li4 + j;
        Bs[kidx][li4 + j] = (k < p.K && n < p.N) ? p.W[(size_t)k * p.N + n] : 0.f;
      }
    }
    __syncthreads();
    #pragma unroll
    for (int kk = 0; kk < 16; ++kk) {
      float4 a = *(const float4*)&As[kk][r0];
      float4 bq = *(const float4*)&Bs[kk][c0];
      float av[4] = {a.x, a.y, a.z, a.w};
      float bv[4] = {bq.x, bq.y, bq.z, bq.w};
      #pragma unroll
      for (int i = 0; i < 4; ++i)
        #pragma unroll
        for (int j = 0; j < 4; ++j)
          acc[i][j] = fmaf(av[i], bv[j], acc[i][j]);
    }
  }
  float eb[4] = {p.ebias[n0 + c0], p.ebias[n0 + c0 + 1], p.ebias[n0 + c0 + 2], p.ebias[n0 + c0 + 3]};
  #pragma unroll
  for (int i = 0; i < 4; ++i) {
    float4 v;
    v.x = softplus_f(acc[i][0] + eb[0]);
    v.y = softplus_f(acc[i][1] + eb[1]);
    v.z = softplus_f(acc[i][2] + eb[2]);
    v.w = softplus_f(acc[i][3] + eb[3]);
    *(float4*)&p.out0[(size_t)(m0 + r0 + i) * p.ldo + n0 + c0] = v;
  }
}

// ---------------------------------------------------------------------------
// Chunked selective scan, token-major. u,z,y bf16 [B*L][Dch]; dlt fp32;
// xdbl fp32 [B*L][64], B at roff.., C at roff+16..
// PF layout [c][slot 0..31][NCH] fp32: slots 0..15 = P, 16..31 = F/Hin.
// ---------------------------------------------------------------------------
template<int PASS>
__global__ __launch_bounds__(64) void scan_tm_k(
    const u16* __restrict__ u, const float* __restrict__ dlt,
    const float* __restrict__ Alog, const float* __restrict__ xdbl, int roff,
    const float* __restrict__ Dp, const u16* __restrict__ zT,
    float* __restrict__ PF, u16* __restrict__ yT,
    int Dch, int CLen, int NCH)
{
  const int d = blockIdx.x * 64 + threadIdx.x;
  const int c = blockIdx.y;
  const int b = blockIdx.z;
  const int ch = b * Dch + d;
  const size_t tok0 = (size_t)b * L + (size_t)c * CLen;
  float An[16], h[16], P[16];
  #pragma unroll
  for (int n = 0; n < 16; ++n) {
    An[n] = -__expf(Alog[d * 16 + n]);
    P[n] = 1.f; h[n] = 0.f;
  }
  if (PASS == 3) {
    #pragma unroll
    for (int n2 = 0; n2 < 16; ++n2)
      h[n2] = PF[((size_t)c * 32 + 16 + n2) * NCH + ch];
  }
  const float Dd = Dp[d];
  const u16* up = u + tok0 * Dch + d;
  const float* dp = dlt + tok0 * Dch + d;
  const u16* zp = zT + tok0 * Dch + d;
  u16* yr = yT + tok0 * Dch + d;
  const float* xr = xdbl + tok0 * 64 + roff;
  for (int t = 0; t < CLen; ++t) {
    const size_t od = (size_t)t * Dch;
    float dl = dp[od];
    float uu = bf2f(up[od]);
    float w = dl * uu;
    const float2* bp = (const float2*)(xr + (size_t)t * 64);
    float y = 0.f;
    #pragma unroll
    for (int q = 0; q < 8; ++q) {
      float2 bv = bp[q];
      float a0 = __expf(dl * An[2 * q]);
      float a1 = __expf(dl * An[2 * q + 1]);
      h[2 * q]     = fmaf(a0, h[2 * q],     w * bv.x);
      h[2 * q + 1] = fmaf(a1, h[2 * q + 1], w * bv.y);
      if (PASS == 1) {
        P[2 * q] *= a0; P[2 * q + 1] *= a1;
      } else {
        float2 cv = bp[q + 8];
        y = fmaf(h[2 * q], cv.x, y);
        y = fmaf(h[2 * q + 1], cv.y, y);
      }
    }
    if (PASS == 3) {
      float zv = bf2f(zp[od]);
      yr[od] = f2bf((y + Dd * uu) * silu_f(zv));
    }
  }
  if (PASS == 1) {
    #pragma unroll
    for (int n2 = 0; n2 < 16; ++n2) {
      PF[((size_t)c * 32 + n2) * NCH + ch] = P[n2];
      PF[((size_t)c * 32 + 16 + n2) * NCH + ch] = h[n2];
    }
  }
}

// Stitch: per (ch, state n) sequential over chunks; rewrites F slot with Hin.
__global__ __launch_bounds__(256) void stitch_k(float* __restrict__ PF,
    int NC, int NCH, int total) {
  int idx = blockIdx.x * 256 + threadIdx.x;
  if (idx >= total) return;
  int ch = idx % NCH, n = idx / NCH;
  float hin = 0.f;
  for (int c = 0; c < NC; ++c) {
    float* Ps = PF + ((size_t)c * 32 + n) * NCH + ch;
    float* Fs = PF + ((size_t)c * 32 + 16 + n) * NCH + ch;
    float Pv = *Ps, Fv = *Fs;
    *Fs = hin;
    hin = fmaf(Pv, hin, Fv);
  }
}

// ---------------------------------------------------------------------------
extern "C" void kernel_launch(void* const* d_in, const int* in_sizes, int n_in,
                              void* d_out, int out_size, void* d_ws, size_t ws_size,
                              hipStream_t stream) {
  const float* m_ll    = (const float*)d_in[0];
  const float* m_high  = (const float*)d_in[1];
  const float* zanc    = (const float*)d_in[2];
  const float* Kin     = (const float*)d_in[3];
  const float* Qin     = (const float*)d_in[4];
  const float* s_in_w  = (const float*)d_in[5];
  const float* s_conv_w= (const float*)d_in[6];
  const float* s_conv_b= (const float*)d_in[7];
  const float* s_x_w   = (const float*)d_in[8];
  const float* s_dt_w  = (const float*)d_in[9];
  const float* s_dt_b  = (const float*)d_in[10];
  const float* s_Alog  = (const float*)d_in[11];
  const float* s_D     = (const float*)d_in[12];
  const float* s_out_w = (const float*)d_in[13];
  const float* t_in_w  = (const float*)d_in[14];
  const float* t_conv_w= (const float*)d_in[15];
  const float* t_conv_b= (const float*)d_in[16];
  const float* t_kln_g = (const float*)d_in[17];
  const float* t_kln_b = (const float*)d_in[18];
  const float* t_k_w   = (const float*)d_in[19];
  const float* t_k_b   = (const float*)d_in[20];
  const float* t_qln_g = (const float*)d_in[21];
  const float* t_qln_b = (const float*)d_in[22];
  const float* t_q_w   = (const float*)d_in[23];
  const float* t_q_b   = (const float*)d_in[24];
  const float* t_dtbc_w= (const float*)d_in[25];
  const float* t_dt_w  = (const float*)d_in[26];
  const float* t_dt_b  = (const float*)d_in[27];
  const float* t_gate_w= (const float*)d_in[28];
  const float* t_gate_b= (const float*)d_in[29];
  const float* t_Alog  = (const float*)d_in[30];
  const float* t_D     = (const float*)d_in[31];
  const float* t_out_w = (const float*)d_in[32];

  float* out1 = (float*)d_out;               // (4, 96, 4096)  = 1,572,864 f
  float* out2 = out1 + (size_t)4 * 96 * L;   // (4, 288, 4096) = 4,718,592 f
  float* ws = (float*)d_ws;

  // Weight region (bf16)
  u16* w_sin   = (u16*)(ws + 0);        // [384][96]
  u16* w_sx    = (u16*)(ws + 18432);    // [128][192]
  u16* w_sout  = (u16*)(ws + 30720);    // [128][192]
  u16* w_tin   = (u16*)(ws + 43008);    // [640][288]
  u16* w_tk    = (u16*)(ws + 135168);   // [640][288]
  u16* w_tq    = (u16*)(ws + 227328);   // [640][288]
  u16* w_tdtbc = (u16*)(ws + 319488);   // [128][1152]
  u16* w_tgate = (u16*)(ws + 393216);   // [640][1152]
  u16* w_tout  = (u16*)(ws + 761856);   // [384][576]
  // Big slots (float offsets)
  float* SA = ws + 872448;    // 4,718,592 f
  float* SB = ws + 5591040;   // 4,718,592 f
  float* SC = ws + 10309632;  // 4,718,592 f
  float* SD = ws + 15028224;  // 4,718,592 f
  float* SE = ws + 19746816;  // 4,718,592 f
  float* SF = ws + 24465408;  // 1,048,576 f
  float* SG = ws + 25513984;  // 2,359,296 f

  dim3 blk(256);
  dim3 blk64(64);
  dim3 tgrid(128, 4);

  // ---- weight conversion (9 segments) ----
  {
    WAll wa;
    wa.s[0] = {s_in_w,   w_sin,    96, 384, 384};
    wa.s[1] = {s_x_w,    w_sx,    192,  38, 128};
    wa.s[2] = {s_out_w,  w_sout,  192,  96, 128};
    wa.s[3] = {t_in_w,   w_tin,   288, 576, 640};
    wa.s[4] = {t_k_w,    w_tk,    288, 576, 640};
    wa.s[5] = {t_q_w,    w_tq,    288, 576, 640};
    wa.s[6] = {t_dtbc_w, w_tdtbc, 1152, 50, 128};
    wa.s[7] = {t_gate_w, w_tgate, 1152, 576, 640};
    wa.s[8] = {t_out_w,  w_tout,  576, 288, 384};
    wconv_k<<<dim3(20, 36, 9), blk, 0, stream>>>(wa);
  }

  // ================= SSS stream =================
  u16* a_ll  = (u16*)SG;                  // [16384][96]
  u16* x_in  = (u16*)SA;                  // [16384][192]
  u16* zTs   = (u16*)(SA + 1572864);      // [16384][192]
  u16* xc    = (u16*)SB;                  // [16384][192]
  float* xdbl = SF;                       // [16384][64]
  float* dlt  = SC;                       // [16384][192] fp32
  u16* y_bf  = (u16*)SD;                  // [16384][192]
  float* PFs  = SE;                       // 128*32*768

  trans_bf_k<0><<<tgrid, blk, 0, stream>>>(m_ll, nullptr, nullptr, zanc, a_ll, 96);
  { MP p{}; p.A0 = a_ll; p.Wt = w_sin; p.K = 96; p.K1 = 1 << 28; p.Nout = 384;
    p.ldA = 96; p.split = 192; p.outB0 = x_in; p.outB1 = zTs; p.nbx = 3;
    mfma_gemm_k<5><<<dim3(3 * 128), blk, 0, stream>>>(p); }
  conv_bf_k<<<dim3(3, 512), blk, 0, stream>>>(x_in, s_conv_w, s_conv_b, xc, 192);
  { MP p{}; p.A0 = xc; p.Wt = w_sx; p.K = 192; p.K1 = 1 << 28; p.Nout = 64;
    p.ldA = 192; p.ldo = 64; p.outF = xdbl; p.nbx = 1;
    mfma_gemm_k<0><<<dim3(128), blk, 0, stream>>>(p); }
  { GemmP p{}; p.A0 = xdbl; p.lda = 64; p.K = 6; p.W = s_dt_w; p.N = 192;
    p.ebias = s_dt_b; p.out0 = dlt; p.ldo = 192;
    gemm_f32_k<<<dim3(3, 256), blk, 0, stream>>>(p); }
  scan_tm_k<1><<<dim3(3, 128, 4), blk64, 0, stream>>>(xc, dlt, s_Alog, xdbl, 6, s_D, zTs, PFs, y_bf, 192, 32, 768);
  stitch_k<<<dim3(48), blk, 0, stream>>>(PFs, 128, 768, 12288);
  scan_tm_k<3><<<dim3(3, 128, 4), blk64, 0, stream>>>(xc, dlt, s_Alog, xdbl, 6, s_D, zTs, PFs, y_bf, 192, 32, 768);
  { MP p{}; p.A0 = y_bf; p.Wt = w_sout; p.K = 192; p.K1 = 1 << 28; p.Nout = 96;
    p.ldA = 192; p.res = m_ll; p.outF = out1; p.nbx = 1;
    mfma_gemm_k<2><<<dim3(128), blk, 0, stream>>>(p); }

  // ================= STS stream =================
  u16* a_hi  = (u16*)SG;                  // [16384][288] (also aK/aQ slot)
  u16* xin3  = (u16*)SA;                  // [16384][576]
  u16* xc3   = (u16*)SB;                  // [16384][576]
  u16* kp    = (u16*)SC;                  // [16384][576]
  u16* qp    = (u16*)SD;                  // [16384][576]
  float* dlt3 = SC;                       // [16384][576] fp32 (over kp+qp)
  u16* zg3   = (u16*)SE;                  // [16384][576]
  float* xdbl3 = SF;                      // [16384][64]
  u16* y3    = (u16*)SA;                  // [16384][576] (over xin3)
  float* PFt = out2;                      // 64*32*2304 == |out2|

  trans_bf_k<0><<<tgrid, blk, 0, stream>>>(m_high, nullptr, nullptr, nullptr, a_hi, 288);
  { MP p{}; p.A0 = a_hi; p.Wt = w_tin; p.K = 288; p.K1 = 1 << 28; p.Nout = 576;
    p.ldA = 288; p.ldo = 576; p.outB0 = xin3; p.nbx = 5;
    mfma_gemm_k<1><<<dim3(5 * 128), blk, 0, stream>>>(p); }
  conv_bf_k<<<dim3(9, 512), blk, 0, stream>>>(xin3, t_conv_w, t_conv_b, xc3, 576);
  trans_bf_k<1><<<tgrid, blk, 0, stream>>>(Kin, t_kln_g, t_kln_b, nullptr, a_hi, 288);
  { MP p{}; p.A0 = a_hi; p.Wt = w_tk; p.K = 288; p.K1 = 1 << 28; p.Nout = 576;
    p.ldA = 288; p.ldo = 576; p.bias = t_k_b; p.outB0 = kp; p.nbx = 5;
    mfma_gemm_k<3><<<dim3(5 * 128), blk, 0, stream>>>(p); }
  trans_bf_k<1><<<tgrid, blk, 0, stream>>>(Qin, t_qln_g, t_qln_b, nullptr, a_hi, 288);
  { MP p{}; p.A0 = a_hi; p.Wt = w_tq; p.K = 288; p.K1 = 1 << 28; p.Nout = 576;
    p.ldA = 288; p.ldo = 576; p.bias = t_q_b; p.outB0 = qp; p.nbx = 5;
    mfma_gemm_k<3><<<dim3(5 * 128), blk, 0, stream>>>(p); }
  { MP p{}; p.A0 = xc3; p.A1 = kp; p.Wt = w_tdtbc; p.K = 1152; p.K1 = 576;
    p.Nout = 64; p.ldA = 576; p.ldo = 64; p.outF = xdbl3; p.nbx = 1;
    mfma_gemm_k<0><<<dim3(128), blk, 0, stream>>>(p); }
  { MP p{}; p.A0 = xc3; p.A1 = qp; p.Wt = w_tgate; p.K = 1152; p.K1 = 576;
    p.Nout = 576; p.ldA = 576; p.ldo = 576; p.bias = t_gate_b; p.outB0 = zg3; p.nbx = 5;
    mfma_gemm_k<4><<<dim3(5 * 128), blk, 0, stream>>>(p); }
  { GemmP p{}; p.A0 = xdbl3; p.lda = 64; p.K = 18; p.W = t_dt_w; p.N = 576;
    p.ebias = t_dt_b; p.out0 = dlt3; p.ldo = 576;
    gemm_f32_k<<<dim3(9, 256), blk, 0, stream>>>(p); }
  scan_tm_k<1><<<dim3(9, 64, 4), blk64, 0, stream>>>(xc3, dlt3, t_Alog, xdbl3, 18, t_D, zg3, PFt, y3, 576, 64, 2304);
  stitch_k<<<dim3(144), blk, 0, stream>>>(PFt, 64, 2304, 36864);
  scan_tm_k<3><<<dim3(9, 64, 4), blk64, 0, stream>>>(xc3, dlt3, t_Alog, xdbl3, 18, t_D, zg3, PFt, y3, 576, 64, 2304);
  { MP p{}; p.A0 = y3; p.Wt = w_tout; p.K = 576; p.K1 = 1 << 28; p.Nout = 288;
    p.ldA = 576; p.res = m_high; p.outF = out2; p.nbx = 3;
    mfma_gemm_k<2><<<dim3(3 * 128), blk, 0, stream>>>(p); }
}

// Round 7
// 476.277 us; speedup vs baseline: 1.2069x; 1.2069x over previous
//
#include <hip/hip_runtime.h>
#include <math.h>

// DualStreamBlock: B=4, DIM=96, DIM3=288, H=W=64, L=4096, DSTATE=16
#define L 4096

typedef unsigned short u16;
typedef float f32x4 __attribute__((ext_vector_type(4)));
typedef short s16x8 __attribute__((ext_vector_type(8)));
typedef __attribute__((address_space(3))) unsigned int lds_u32;
typedef __attribute__((address_space(1))) unsigned int glb_u32;

__device__ __forceinline__ float softplus_f(float x) {
  return fmaxf(x, 0.f) + log1pf(__expf(-fabsf(x)));
}
__device__ __forceinline__ float silu_f(float x) {
  return x / (1.f + __expf(-x));
}
__device__ __forceinline__ float bf2f(u16 v) {
  return __uint_as_float(((unsigned)v) << 16);
}
__device__ __forceinline__ u16 f2bf(float f) {
  unsigned u = __float_as_uint(f);
  u += 0x7FFFu + ((u >> 16) & 1u);
  return (u16)(u >> 16);
}

// ---------------------------------------------------------------------------
// Weight convert: fp32 W[K][N] -> bf16 Wt[Npad][K] (transposed, zero-padded)
// ---------------------------------------------------------------------------
struct WSeg { const float* src; u16* dst; int K, N, Npad; };
struct WAll { WSeg s[9]; };

__global__ __launch_bounds__(256) void wconv_k(WAll wa) {
  const WSeg w = wa.s[blockIdx.z];
  const int nb = blockIdx.x * 32, kb = blockIdx.y * 32;
  if (nb >= w.Npad || kb >= w.K) return;
  __shared__ float t[32][33];
  const int tx = threadIdx.x & 31, ty = threadIdx.x >> 5;
  for (int r = ty; r < 32; r += 8) {
    int k = kb + r, n = nb + tx;
    t[r][tx] = (n < w.N) ? w.src[(size_t)k * w.N + n] : 0.f;
  }
  __syncthreads();
  for (int r = ty; r < 32; r += 8) {
    int n = nb + r;
    w.dst[(size_t)n * w.K + kb + tx] = f2bf(t[tx][r]);
  }
}

// ---------------------------------------------------------------------------
// Packed transpose prep: 4 segments x 512 blocks. chan-major fp32 -> token-major
// bf16. Per-segment: optional LN over C, optional +bias2[b*C+c].
// ---------------------------------------------------------------------------
struct TSeg { const float *x, *gam, *bet, *bias2; u16* out; int C, doLN; };
struct TPack { TSeg s[4]; };

__global__ __launch_bounds__(256) void trans_pack_k(TPack pk) {
  const TSeg t = pk.s[blockIdx.x >> 9];
  const int local = blockIdx.x & 511;
  const int C = t.C;
  __shared__ float tile[288][33];
  __shared__ float psum[8][32], psq[8][32];
  __shared__ float mm[32], rr[32];
  const int tid = threadIdx.x;
  const int l0 = (local & 127) * 32;
  const int b = local >> 7;
  const int lane32 = tid & 31, row8 = tid >> 5;
  const float* xb = t.x + (size_t)b * C * L + l0;

  for (int c = row8; c < C; c += 8)
    tile[c][lane32] = xb[(size_t)c * L + lane32];
  __syncthreads();

  if (t.doLN) {
    float s = 0.f, sq = 0.f;
    for (int c = row8; c < C; c += 8) {
      float v = tile[c][lane32];
      s += v; sq = fmaf(v, v, sq);
    }
    psum[row8][lane32] = s; psq[row8][lane32] = sq;
    __syncthreads();
    if (row8 == 0) {
      float ts = 0.f, tq = 0.f;
      #pragma unroll
      for (int g = 0; g < 8; ++g) { ts += psum[g][lane32]; tq += psq[g][lane32]; }
      float m = ts / C;
      float var = tq / C - m * m;
      mm[lane32] = m;
      rr[lane32] = rsqrtf(var + 1e-5f);
    }
    __syncthreads();
  }

  u16* ob = t.out + ((size_t)b * L + l0) * C;
  const int total = 32 * C;
  for (int o = tid * 8; o < total; o += 2048) {
    int tt = o / C, c = o % C;
    float m = 0.f, rs = 0.f;
    if (t.doLN) { m = mm[tt]; rs = rr[tt]; }
    union { u16 u[8]; int4 v; } pkv;
    #pragma unroll
    for (int j = 0; j < 8; ++j) {
      float v = tile[c + j][tt];
      if (t.doLN) v = (v - m) * rs * t.gam[c + j] + t.bet[c + j];
      else if (t.bias2) v += t.bias2[b * C + c + j];
      pkv.u[j] = f2bf(v);
    }
    *(int4*)(ob + o) = pkv.v;
  }
}

// ---------------------------------------------------------------------------
// Packed causal depthwise conv k=4 + bias + silu, token-major bf16 (2 segments)
// ---------------------------------------------------------------------------
struct CSeg { const u16* x; const float* w; const float* b; u16* y; int C, nbx; };
struct CPack { CSeg s[2]; int start1; };

__global__ __launch_bounds__(256) void conv_pack_k(CPack pk) {
  const int bid = blockIdx.x;
  const int si = bid >= pk.start1;
  const CSeg q = pk.s[si];
  const int local = si ? bid - pk.start1 : bid;
  const int C = q.C;
  const int c = (local % q.nbx) * 64 + (threadIdx.x & 63);
  const int chunk = (local / q.nbx) * 4 + (threadIdx.x >> 6);
  const int T0 = chunk * 8;
  const float w0 = q.w[c * 4], w1 = q.w[c * 4 + 1], w2 = q.w[c * 4 + 2], w3 = q.w[c * 4 + 3];
  const float bs = q.b[c];
  const bool first = (T0 & (L - 1)) == 0;
  float v[11];
  #pragma unroll
  for (int i = 0; i < 11; ++i) {
    if (i < 3 && first) v[i] = 0.f;
    else v[i] = bf2f(q.x[(size_t)(T0 - 3 + i) * C + c]);
  }
  #pragma unroll
  for (int j = 0; j < 8; ++j) {
    float s = bs + w0 * v[j] + w1 * v[j + 1] + w2 * v[j + 2] + w3 * v[j + 3];
    q.y[(size_t)(T0 + j) * C + c] = f2bf(silu_f(s));
  }
}

// ---------------------------------------------------------------------------
// Packed MFMA bf16 GEMM (up to 4 segments). Tile 128x128, 4 waves, BK=32,
// 2-stage double-buffer (32KB LDS -> up to 5 blocks/CU), global_load_lds,
// per-segment XCD-bijective swizzle with m-major chunking.
// epi: 0 fp32 row-major; 1 bf16 row-major; 2 chan-major fp32 + residual;
//      3 silu(x+bias) bf16; 4 (x+bias) bf16; 5 split bf16 (outB0|outB1).
// ---------------------------------------------------------------------------
struct MSeg {
  const u16 *A0, *A1, *Wt;
  const float *bias, *res;
  float* outF; u16 *outB0, *outB1;
  int K, K1, Nout, ldA, ldo, split, nbx, nwg, epi;
};
struct MPack { MSeg s[4]; int starts[4]; int nseg; };

__global__ __launch_bounds__(256) void mfma_pack_k(MPack pk) {
  const int bid = blockIdx.x;
  int si = 0;
  #pragma unroll
  for (int k = 1; k < 4; ++k)
    if (k < pk.nseg && bid >= pk.starts[k]) si = k;
  const MSeg p = pk.s[si];
  const int wg = bid - pk.starts[si];

  __shared__ u16 As[2][4096];
  __shared__ u16 Bs[2][4096];
  const int tid = threadIdx.x;
  const int lane = tid & 63;
  const int wid = tid >> 6;
  const int wm = wid >> 1, wn = wid & 1;
  const int newid = (wg & 7) * (p.nwg >> 3) + (wg >> 3);
  const int n0 = (newid % p.nbx) * 128;
  const int m0 = (newid / p.nbx) * 128;
  const int srow = tid & 127;
  const int skc = tid >> 7;
  const int kgrp = lane >> 4, l16 = lane & 15;

  f32x4 acc[4][4];
  #pragma unroll
  for (int i = 0; i < 4; ++i)
    #pragma unroll
    for (int j = 0; j < 4; ++j)
      acc[i][j] = (f32x4){0.f, 0.f, 0.f, 0.f};

  auto stage = [&](int bi, int k0) {
    const u16* Ab = p.A0;
    int kc = k0;
    if (p.A1 && k0 >= p.K1) { Ab = p.A1; kc = k0 - p.K1; }
    const u16* g0 = Ab + (size_t)(m0 + srow) * p.ldA + kc + skc * 8;
    u16* Ad = &As[bi][0];
    __builtin_amdgcn_global_load_lds((const glb_u32*)g0,
        (lds_u32*)(Ad + wid * 512), 16, 0, 0);
    __builtin_amdgcn_global_load_lds((const glb_u32*)(g0 + 16),
        (lds_u32*)(Ad + 2048 + wid * 512), 16, 0, 0);
    const u16* h0 = p.Wt + (size_t)(n0 + srow) * p.K + k0 + skc * 8;
    u16* Bd = &Bs[bi][0];
    __builtin_amdgcn_global_load_lds((const glb_u32*)h0,
        (lds_u32*)(Bd + wid * 512), 16, 0, 0);
    __builtin_amdgcn_global_load_lds((const glb_u32*)(h0 + 16),
        (lds_u32*)(Bd + 2048 + wid * 512), 16, 0, 0);
  };

  const int nt = p.K >> 5;
  stage(0, 0);
  __syncthreads();
  for (int t = 0; t < nt; ++t) {
    const int cur = t & 1;
    if (t + 1 < nt) stage(cur ^ 1, (t + 1) << 5);
    s16x8 af[4], bfr[4];
    #pragma unroll
    for (int mi = 0; mi < 4; ++mi)
      af[mi] = *(const s16x8*)(&As[cur][0] + kgrp * 1024 + (wm * 64 + mi * 16 + l16) * 8);
    #pragma unroll
    for (int ni = 0; ni < 4; ++ni)
      bfr[ni] = *(const s16x8*)(&Bs[cur][0] + kgrp * 1024 + (wn * 64 + ni * 16 + l16) * 8);
    #pragma unroll
    for (int mi = 0; mi < 4; ++mi)
      #pragma unroll
      for (int ni = 0; ni < 4; ++ni)
        acc[mi][ni] = __builtin_amdgcn_mfma_f32_16x16x32_bf16(af[mi], bfr[ni], acc[mi][ni], 0, 0, 0);
    if (t + 1 < nt) __syncthreads();
  }

  if (p.epi == 2) {
    #pragma unroll
    for (int mi = 0; mi < 4; ++mi) {
      int token = m0 + wm * 64 + mi * 16 + (lane >> 4) * 4;
      int b = token >> 12, l = token & (L - 1);
      #pragma unroll
      for (int ni = 0; ni < 4; ++ni) {
        int n = n0 + wn * 64 + ni * 16 + l16;
        if (n < p.Nout) {
          size_t o = ((size_t)b * p.Nout + n) * L + l;
          float4 r = *(const float4*)(p.res + o);
          float4 v = make_float4(acc[mi][ni][0] + r.x, acc[mi][ni][1] + r.y,
                                 acc[mi][ni][2] + r.z, acc[mi][ni][3] + r.w);
          *(float4*)(p.outF + o) = v;
        }
      }
    }
  } else {
    #pragma unroll
    for (int mi = 0; mi < 4; ++mi) {
      #pragma unroll
      for (int j = 0; j < 4; ++j) {
        int token = m0 + wm * 64 + mi * 16 + (lane >> 4) * 4 + j;
        #pragma unroll
        for (int ni = 0; ni < 4; ++ni) {
          int n = n0 + wn * 64 + ni * 16 + l16;
          float v = acc[mi][ni][j];
          if (p.epi == 0) {
            if (n < p.Nout) p.outF[(size_t)token * p.ldo + n] = v;
          } else if (p.epi == 1) {
            if (n < p.Nout) p.outB0[(size_t)token * p.ldo + n] = f2bf(v);
          } else if (p.epi == 3) {
            if (n < p.Nout) p.outB0[(size_t)token * p.ldo + n] = f2bf(silu_f(v + p.bias[n]));
          } else if (p.epi == 4) {
            if (n < p.Nout) p.outB0[(size_t)token * p.ldo + n] = f2bf(v + p.bias[n]);
          } else {  // 5: split
            if (n < p.split) p.outB0[(size_t)token * p.split + n] = f2bf(v);
            else p.outB1[(size_t)token * p.split + (n - p.split)] = f2bf(v);
          }
        }
      }
    }
  }
}

// ---------------------------------------------------------------------------
// Packed small fp32 GEMM (dt projections): softplus(x + eb[n]) epilogue
// ---------------------------------------------------------------------------
struct FSeg { const float* A0; const float* W; const float* eb; float* out; int K, N, lda, ldo, nbx; };
struct FPack { FSeg s[2]; int start1; };

__global__ __launch_bounds__(256) void gemm_f32_pack_k(FPack pk) {
  const int bid = blockIdx.x;
  const int si = bid >= pk.start1;
  const FSeg p = pk.s[si];
  const int local = si ? bid - pk.start1 : bid;
  const int n0 = (local % p.nbx) * 64;
  const int m0 = (local / p.nbx) * 64;

  __shared__ __align__(16) float As[16][64];
  __shared__ __align__(16) float Bs[16][64];
  const int tid = threadIdx.x;
  const int kidx = tid >> 4;
  const int li4 = (tid & 15) << 2;
  const int r0 = (tid & 15) << 2;
  const int c0 = (tid >> 4) << 2;
  float acc[4][4] = {};

  for (int k0 = 0; k0 < p.K; k0 += 16) {
    __syncthreads();
    {
      const int row = tid >> 2;
      const int kk4 = (tid & 3) << 2;
      const float* src = p.A0 + (size_t)(m0 + row) * p.lda;
      #pragma unroll
      for (int j = 0; j < 4; ++j) {
        int k = k0 + kk4 + j;
        As[kk4 + j][row] = (k < p.K) ? src[k] : 0.f;
      }
    }
    {
      int k = k0 + kidx;
      #pragma unroll
      for (int j = 0; j < 4; ++j) {
        int n = n0 + li4 + j;
        Bs[kidx][li4 + j] = (k < p.K && n < p.N) ? p.W[(size_t)k * p.N + n] : 0.f;
      }
    }
    __syncthreads();
    #pragma unroll
    for (int kk = 0; kk < 16; ++kk) {
      float4 a = *(const float4*)&As[kk][r0];
      float4 bq = *(const float4*)&Bs[kk][c0];
      float av[4] = {a.x, a.y, a.z, a.w};
      float bv[4] = {bq.x, bq.y, bq.z, bq.w};
      #pragma unroll
      for (int i = 0; i < 4; ++i)
        #pragma unroll
        for (int j = 0; j < 4; ++j)
          acc[i][j] = fmaf(av[i], bv[j], acc[i][j]);
    }
  }
  float eb[4] = {p.eb[n0 + c0], p.eb[n0 + c0 + 1], p.eb[n0 + c0 + 2], p.eb[n0 + c0 + 3]};
  #pragma unroll
  for (int i = 0; i < 4; ++i) {
    float4 v;
    v.x = softplus_f(acc[i][0] + eb[0]);
    v.y = softplus_f(acc[i][1] + eb[1]);
    v.z = softplus_f(acc[i][2] + eb[2]);
    v.w = softplus_f(acc[i][3] + eb[3]);
    *(float4*)&p.out[(size_t)(m0 + r0 + i) * p.ldo + n0 + c0] = v;
  }
}

// ---------------------------------------------------------------------------
// Packed chunked selective scan (2 segments). Token-major u,z,y bf16; dlt fp32;
// xdbl fp32 [B*L][64] (B at roff, C at roff+16).
// PF layout [c][slot 0..31][NCH] fp32: slots 0..15 = P, 16..31 = F/Hin.
// PASS 1: compute P, F (h_in = 0). PASS 3: h_in = Hin, emit y.
// ---------------------------------------------------------------------------
struct SSeg {
  const u16* u; const float* dlt; const float* Alog; const float* xdbl;
  const float* Dp; const u16* zT; float* PF; u16* yT;
  int roff, Dch, CLen, NCH, nxc;
};
struct SPack { SSeg s[2]; int start1; };

template<int PASS>
__global__ __launch_bounds__(64) void scan_pack_k(SPack pk) {
  const int bid = blockIdx.x;
  const int si = bid >= pk.start1;
  const SSeg q = pk.s[si];
  const int local = si ? bid - pk.start1 : bid;
  const int NC = L / q.CLen;
  const int d = (local % q.nxc) * 64 + threadIdx.x;
  const int c = (local / q.nxc) % NC;
  const int b = local / (q.nxc * NC);
  const int Dch = q.Dch;
  const int ch = b * Dch + d;
  const size_t tok0 = (size_t)b * L + (size_t)c * q.CLen;
  float An[16], h[16], P[16];
  #pragma unroll
  for (int n = 0; n < 16; ++n) {
    An[n] = -__expf(q.Alog[d * 16 + n]);
    P[n] = 1.f; h[n] = 0.f;
  }
  if (PASS == 3) {
    #pragma unroll
    for (int n2 = 0; n2 < 16; ++n2)
      h[n2] = q.PF[((size_t)c * 32 + 16 + n2) * q.NCH + ch];
  }
  const float Dd = q.Dp[d];
  const u16* up = q.u + tok0 * Dch + d;
  const float* dp = q.dlt + tok0 * Dch + d;
  const u16* zp = q.zT + tok0 * Dch + d;
  u16* yr = q.yT + tok0 * Dch + d;
  const float* xr = q.xdbl + tok0 * 64 + q.roff;
  for (int t = 0; t < q.CLen; ++t) {
    const size_t od = (size_t)t * Dch;
    float dl = dp[od];
    float uu = bf2f(up[od]);
    float w = dl * uu;
    const float2* bp = (const float2*)(xr + (size_t)t * 64);
    float y = 0.f;
    #pragma unroll
    for (int qq = 0; qq < 8; ++qq) {
      float2 bv = bp[qq];
      float a0 = __expf(dl * An[2 * qq]);
      float a1 = __expf(dl * An[2 * qq + 1]);
      h[2 * qq]     = fmaf(a0, h[2 * qq],     w * bv.x);
      h[2 * qq + 1] = fmaf(a1, h[2 * qq + 1], w * bv.y);
      if (PASS == 1) {
        P[2 * qq] *= a0; P[2 * qq + 1] *= a1;
      } else {
        float2 cv = bp[qq + 8];
        y = fmaf(h[2 * qq], cv.x, y);
        y = fmaf(h[2 * qq + 1], cv.y, y);
      }
    }
    if (PASS == 3) {
      float zv = bf2f(zp[od]);
      yr[od] = f2bf((y + Dd * uu) * silu_f(zv));
    }
  }
  if (PASS == 1) {
    #pragma unroll
    for (int n2 = 0; n2 < 16; ++n2) {
      q.PF[((size_t)c * 32 + n2) * q.NCH + ch] = P[n2];
      q.PF[((size_t)c * 32 + 16 + n2) * q.NCH + ch] = h[n2];
    }
  }
}

// Packed stitch: per (ch, state) sequential over chunks; rewrites F with Hin.
__global__ __launch_bounds__(256) void stitch_pack_k(
    float* PF0, int NC0, int NCH0, int tot0,
    float* PF1, int NC1, int NCH1, int tot1) {
  int idx = blockIdx.x * 256 + threadIdx.x;
  float* PF; int NC, NCH;
  if (idx < tot0) { PF = PF0; NC = NC0; NCH = NCH0; }
  else { idx -= tot0; if (idx >= tot1) return; PF = PF1; NC = NC1; NCH = NCH1; }
  int ch = idx % NCH, n = idx / NCH;
  float hin = 0.f;
  for (int c = 0; c < NC; ++c) {
    float* Ps = PF + ((size_t)c * 32 + n) * NCH + ch;
    float* Fs = PF + ((size_t)c * 32 + 16 + n) * NCH + ch;
    float Pv = *Ps, Fv = *Fs;
    *Fs = hin;
    hin = fmaf(Pv, hin, Fv);
  }
}

// ---------------------------------------------------------------------------
extern "C" void kernel_launch(void* const* d_in, const int* in_sizes, int n_in,
                              void* d_out, int out_size, void* d_ws, size_t ws_size,
                              hipStream_t stream) {
  const float* m_ll    = (const float*)d_in[0];
  const float* m_high  = (const float*)d_in[1];
  const float* zanc    = (const float*)d_in[2];
  const float* Kin     = (const float*)d_in[3];
  const float* Qin     = (const float*)d_in[4];
  const float* s_in_w  = (const float*)d_in[5];
  const float* s_conv_w= (const float*)d_in[6];
  const float* s_conv_b= (const float*)d_in[7];
  const float* s_x_w   = (const float*)d_in[8];
  const float* s_dt_w  = (const float*)d_in[9];
  const float* s_dt_b  = (const float*)d_in[10];
  const float* s_Alog  = (const float*)d_in[11];
  const float* s_D     = (const float*)d_in[12];
  const float* s_out_w = (const float*)d_in[13];
  const float* t_in_w  = (const float*)d_in[14];
  const float* t_conv_w= (const float*)d_in[15];
  const float* t_conv_b= (const float*)d_in[16];
  const float* t_kln_g = (const float*)d_in[17];
  const float* t_kln_b = (const float*)d_in[18];
  const float* t_k_w   = (const float*)d_in[19];
  const float* t_k_b   = (const float*)d_in[20];
  const float* t_qln_g = (const float*)d_in[21];
  const float* t_qln_b = (const float*)d_in[22];
  const float* t_q_w   = (const float*)d_in[23];
  const float* t_q_b   = (const float*)d_in[24];
  const float* t_dtbc_w= (const float*)d_in[25];
  const float* t_dt_w  = (const float*)d_in[26];
  const float* t_dt_b  = (const float*)d_in[27];
  const float* t_gate_w= (const float*)d_in[28];
  const float* t_gate_b= (const float*)d_in[29];
  const float* t_Alog  = (const float*)d_in[30];
  const float* t_D     = (const float*)d_in[31];
  const float* t_out_w = (const float*)d_in[32];

  float* out1 = (float*)d_out;               // (4, 96, 4096)
  float* out2 = out1 + (size_t)4 * 96 * L;   // (4, 288, 4096) = 4,718,592 f
  float* ws = (float*)d_ws;

  // Weights (bf16)
  u16* w_sin   = (u16*)(ws + 0);        // [384][96]
  u16* w_sx    = (u16*)(ws + 18432);    // [128][192]
  u16* w_sout  = (u16*)(ws + 30720);    // [128][192]
  u16* w_tin   = (u16*)(ws + 43008);    // [640][288]
  u16* w_tk    = (u16*)(ws + 135168);   // [640][288]
  u16* w_tq    = (u16*)(ws + 227328);   // [640][288]
  u16* w_tdtbc = (u16*)(ws + 319488);   // [128][1152]
  u16* w_tgate = (u16*)(ws + 393216);   // [640][1152]
  u16* w_tout  = (u16*)(ws + 761856);   // [384][576]

  // Activations (float offsets; both streams live simultaneously now)
  float* B_ahi  = ws + 872448;    // a_hi  u16[16384][288] (1,179,648 f)
  float* B_aK   = ws + 2052096;   // aK
  float* B_aQ   = ws + 3231744;   // aQ
  float* B_all  = ws + 4411392;   // a_ll u16[16384][96] (786,432 f)
  float* B_xin  = ws + 5197824;   // x_in u16[16384][192] (1,572,864 f)
  float* B_zTs  = ws + 6770688;   // zTs  u16[16384][192]
  float* B_xc   = ws + 8343552;   // xc   u16[16384][192]
  float* B_xin3 = ws + 9916416;   // xin3 u16[16384][576] (4,718,592 f)
  float* B_xc3  = ws + 14635008;  // xc3
  float* B_kp   = ws + 19353600;  // kp
  float* B_qp   = ws + 24072192;  // qp
  float* B_zg3  = ws + 28790784;  // zg3
  float* B_xdbl = ws + 33509376;  // fp32 [16384][64]
  float* B_xdbl3= ws + 34557952;  // fp32 [16384][64]
  float* B_PFs  = ws + 35606528;  // fp32 128*32*768 (ends 38,752,256)
  // Overlays (liveness-checked):
  float* B_dlt  = B_ahi;          // fp32 [16384][192] over a_hi..aQ (dead after P1)
  float* B_dlt3 = B_kp;           // fp32 [16384][576] over kp+qp (dead after P2)
  u16* y_bf = (u16*)B_xin;        // over x_in (dead after conv)
  u16* y3   = (u16*)B_xin3;       // over xin3 (dead after conv)
  float* PFt = out2;              // 64*32*2304 == |out2| (dead until P3)

  dim3 blk(256);

  // 1) weight conversion
  {
    WAll wa;
    wa.s[0] = {s_in_w,   w_sin,    96, 384, 384};
    wa.s[1] = {s_x_w,    w_sx,    192,  38, 128};
    wa.s[2] = {s_out_w,  w_sout,  192,  96, 128};
    wa.s[3] = {t_in_w,   w_tin,   288, 576, 640};
    wa.s[4] = {t_k_w,    w_tk,    288, 576, 640};
    wa.s[5] = {t_q_w,    w_tq,    288, 576, 640};
    wa.s[6] = {t_dtbc_w, w_tdtbc, 1152, 50, 128};
    wa.s[7] = {t_gate_w, w_tgate, 1152, 576, 640};
    wa.s[8] = {t_out_w,  w_tout,  576, 288, 384};
    wconv_k<<<dim3(20, 36, 9), blk, 0, stream>>>(wa);
  }

  // 2) all four transpose-preps in one dispatch (4 x 512 blocks)
  {
    TPack tp{};
    tp.s[0] = {m_ll,   nullptr, nullptr, zanc,    (u16*)B_all, 96,  0};
    tp.s[1] = {m_high, nullptr, nullptr, nullptr, (u16*)B_ahi, 288, 0};
    tp.s[2] = {Kin,    t_kln_g, t_kln_b, nullptr, (u16*)B_aK,  288, 1};
    tp.s[3] = {Qin,    t_qln_g, t_qln_b, nullptr, (u16*)B_aQ,  288, 1};
    trans_pack_k<<<dim3(2048), blk, 0, stream>>>(tp);
  }

  // 3) P1: s_in + t_in + t_k + t_q (2304 blocks)
  {
    MPack pk{}; pk.nseg = 4;
    pk.starts[0] = 0; pk.starts[1] = 384; pk.starts[2] = 1024; pk.starts[3] = 1664;
    MSeg a{}; a.A0 = (u16*)B_all; a.Wt = w_sin; a.K = 96; a.K1 = 1 << 28; a.Nout = 384;
    a.ldA = 96; a.split = 192; a.outB0 = (u16*)B_xin; a.outB1 = (u16*)B_zTs;
    a.nbx = 3; a.nwg = 384; a.epi = 5; pk.s[0] = a;
    MSeg b{}; b.A0 = (u16*)B_ahi; b.Wt = w_tin; b.K = 288; b.K1 = 1 << 28; b.Nout = 576;
    b.ldA = 288; b.ldo = 576; b.outB0 = (u16*)B_xin3; b.nbx = 5; b.nwg = 640; b.epi = 1; pk.s[1] = b;
    MSeg c{}; c.A0 = (u16*)B_aK; c.Wt = w_tk; c.K = 288; c.K1 = 1 << 28; c.Nout = 576;
    c.ldA = 288; c.ldo = 576; c.bias = t_k_b; c.outB0 = (u16*)B_kp; c.nbx = 5; c.nwg = 640; c.epi = 3; pk.s[2] = c;
    MSeg d{}; d.A0 = (u16*)B_aQ; d.Wt = w_tq; d.K = 288; d.K1 = 1 << 28; d.Nout = 576;
    d.ldA = 288; d.ldo = 576; d.bias = t_q_b; d.outB0 = (u16*)B_qp; d.nbx = 5; d.nwg = 640; d.epi = 3; pk.s[3] = d;
    mfma_pack_k<<<dim3(2304), blk, 0, stream>>>(pk);
  }

  // 4) both convs (1536 + 4608 blocks)
  {
    CPack cp{}; cp.start1 = 1536;
    cp.s[0] = {(u16*)B_xin,  s_conv_w, s_conv_b, (u16*)B_xc,  192, 3};
    cp.s[1] = {(u16*)B_xin3, t_conv_w, t_conv_b, (u16*)B_xc3, 576, 9};
    conv_pack_k<<<dim3(6144), blk, 0, stream>>>(cp);
  }

  // 5) P2: s_x + dtbc + gate (896 blocks)
  {
    MPack pk{}; pk.nseg = 3;
    pk.starts[0] = 0; pk.starts[1] = 128; pk.starts[2] = 256; pk.starts[3] = 896;
    MSeg a{}; a.A0 = (u16*)B_xc; a.Wt = w_sx; a.K = 192; a.K1 = 1 << 28; a.Nout = 64;
    a.ldA = 192; a.ldo = 64; a.outF = B_xdbl; a.nbx = 1; a.nwg = 128; a.epi = 0; pk.s[0] = a;
    MSeg b{}; b.A0 = (u16*)B_xc3; b.A1 = (u16*)B_kp; b.Wt = w_tdtbc; b.K = 1152; b.K1 = 576;
    b.Nout = 64; b.ldA = 576; b.ldo = 64; b.outF = B_xdbl3; b.nbx = 1; b.nwg = 128; b.epi = 0; pk.s[1] = b;
    MSeg c{}; c.A0 = (u16*)B_xc3; c.A1 = (u16*)B_qp; c.Wt = w_tgate; c.K = 1152; c.K1 = 576;
    c.Nout = 576; c.ldA = 576; c.ldo = 576; c.bias = t_gate_b; c.outB0 = (u16*)B_zg3;
    c.nbx = 5; c.nwg = 640; c.epi = 4; pk.s[2] = c;
    mfma_pack_k<<<dim3(896), blk, 0, stream>>>(pk);
  }

  // 6) both dt-projection fp32 GEMMs (768 + 2304 blocks)
  {
    FPack fp{}; fp.start1 = 768;
    fp.s[0] = {B_xdbl,  s_dt_w, s_dt_b, B_dlt,  6,  192, 64, 192, 3};
    fp.s[1] = {B_xdbl3, t_dt_w, t_dt_b, B_dlt3, 18, 576, 64, 576, 9};
    gemm_f32_pack_k<<<dim3(3072), blk, 0, stream>>>(fp);
  }

  // 7-9) scans + stitch, both streams packed
  SPack sp{}; sp.start1 = 1536;
  sp.s[0] = {(u16*)B_xc,  B_dlt,  s_Alog, B_xdbl,  s_D, (u16*)B_zTs, B_PFs, y_bf, 6,  192, 32, 768,  3};
  sp.s[1] = {(u16*)B_xc3, B_dlt3, t_Alog, B_xdbl3, t_D, (u16*)B_zg3, PFt,   y3,   18, 576, 64, 2304, 9};
  scan_pack_k<1><<<dim3(3840), dim3(64), 0, stream>>>(sp);
  stitch_pack_k<<<dim3(192), blk, 0, stream>>>(B_PFs, 128, 768, 12288, PFt, 64, 2304, 36864);
  scan_pack_k<3><<<dim3(3840), dim3(64), 0, stream>>>(sp);

  // 10) P3: s_out + t_out (512 blocks)
  {
    MPack pk{}; pk.nseg = 2;
    pk.starts[0] = 0; pk.starts[1] = 128; pk.starts[2] = 512; pk.starts[3] = 512;
    MSeg a{}; a.A0 = y_bf; a.Wt = w_sout; a.K = 192; a.K1 = 1 << 28; a.Nout = 96;
    a.ldA = 192; a.res = m_ll; a.outF = out1; a.nbx = 1; a.nwg = 128; a.epi = 2; pk.s[0] = a;
    MSeg b{}; b.A0 = y3; b.Wt = w_tout; b.K = 576; b.K1 = 1 << 28; b.Nout = 288;
    b.ldA = 576; b.res = m_high; b.outF = out2; b.nbx = 3; b.nwg = 384; b.epi = 2; pk.s[1] = b;
    mfma_pack_k<<<dim3(512), blk, 0, stream>>>(pk);
  }
}

// Round 8
// 428.777 us; speedup vs baseline: 1.3406x; 1.1108x over previous
//
#include <hip/hip_runtime.h>
#include <math.h>

// DualStreamBlock: B=4, DIM=96, DIM3=288, H=W=64, L=4096, DSTATE=16
#define L 4096

typedef unsigned short u16;
typedef unsigned int u32;
typedef float f32x4 __attribute__((ext_vector_type(4)));
typedef short s16x8 __attribute__((ext_vector_type(8)));
typedef __attribute__((address_space(3))) unsigned int lds_u32;
typedef __attribute__((address_space(1))) unsigned int glb_u32;

__device__ __forceinline__ float softplus_f(float x) {
  return fmaxf(x, 0.f) + log1pf(__expf(-fabsf(x)));
}
__device__ __forceinline__ float silu_f(float x) {
  return x / (1.f + __expf(-x));
}
__device__ __forceinline__ float bf2f(u16 v) {
  return __uint_as_float(((unsigned)v) << 16);
}
__device__ __forceinline__ u16 f2bf(float f) {
  unsigned u = __float_as_uint(f);
  u += 0x7FFFu + ((u >> 16) & 1u);
  return (u16)(u >> 16);
}

// ---------------------------------------------------------------------------
// Weight convert: fp32 W[K][N] -> bf16 Wt[Npad][K] (transposed, zero-padded)
// ---------------------------------------------------------------------------
struct WSeg { const float* src; u16* dst; int K, N, Npad; };
struct WAll { WSeg s[9]; };

__global__ __launch_bounds__(256) void wconv_k(WAll wa) {
  const WSeg w = wa.s[blockIdx.z];
  const int nb = blockIdx.x * 32, kb = blockIdx.y * 32;
  if (nb >= w.Npad || kb >= w.K) return;
  __shared__ float t[32][33];
  const int tx = threadIdx.x & 31, ty = threadIdx.x >> 5;
  for (int r = ty; r < 32; r += 8) {
    int k = kb + r, n = nb + tx;
    t[r][tx] = (n < w.N) ? w.src[(size_t)k * w.N + n] : 0.f;
  }
  __syncthreads();
  for (int r = ty; r < 32; r += 8) {
    int n = nb + r;
    w.dst[(size_t)n * w.K + kb + tx] = f2bf(t[tx][r]);
  }
}

// ---------------------------------------------------------------------------
// Packed transpose prep: 4 segments x 512 blocks. chan-major fp32 -> token-major
// bf16. Per-segment: optional LN over C, optional +bias2[b*C+c].
// ---------------------------------------------------------------------------
struct TSeg { const float *x, *gam, *bet, *bias2; u16* out; int C, doLN; };
struct TPack { TSeg s[4]; };

__global__ __launch_bounds__(256) void trans_pack_k(TPack pk) {
  const TSeg t = pk.s[blockIdx.x >> 9];
  const int local = blockIdx.x & 511;
  const int C = t.C;
  __shared__ float tile[288][33];
  __shared__ float psum[8][32], psq[8][32];
  __shared__ float mm[32], rr[32];
  const int tid = threadIdx.x;
  const int l0 = (local & 127) * 32;
  const int b = local >> 7;
  const int lane32 = tid & 31, row8 = tid >> 5;
  const float* xb = t.x + (size_t)b * C * L + l0;

  for (int c = row8; c < C; c += 8)
    tile[c][lane32] = xb[(size_t)c * L + lane32];
  __syncthreads();

  if (t.doLN) {
    float s = 0.f, sq = 0.f;
    for (int c = row8; c < C; c += 8) {
      float v = tile[c][lane32];
      s += v; sq = fmaf(v, v, sq);
    }
    psum[row8][lane32] = s; psq[row8][lane32] = sq;
    __syncthreads();
    if (row8 == 0) {
      float ts = 0.f, tq = 0.f;
      #pragma unroll
      for (int g = 0; g < 8; ++g) { ts += psum[g][lane32]; tq += psq[g][lane32]; }
      float m = ts / C;
      float var = tq / C - m * m;
      mm[lane32] = m;
      rr[lane32] = rsqrtf(var + 1e-5f);
    }
    __syncthreads();
  }

  u16* ob = t.out + ((size_t)b * L + l0) * C;
  const int total = 32 * C;
  for (int o = tid * 8; o < total; o += 2048) {
    int tt = o / C, c = o % C;
    float m = 0.f, rs = 0.f;
    if (t.doLN) { m = mm[tt]; rs = rr[tt]; }
    union { u16 u[8]; int4 v; } pkv;
    #pragma unroll
    for (int j = 0; j < 8; ++j) {
      float v = tile[c + j][tt];
      if (t.doLN) v = (v - m) * rs * t.gam[c + j] + t.bet[c + j];
      else if (t.bias2) v += t.bias2[b * C + c + j];
      pkv.u[j] = f2bf(v);
    }
    *(int4*)(ob + o) = pkv.v;
  }
}

// ---------------------------------------------------------------------------
// Packed causal depthwise conv k=4 + bias + silu, token-major bf16 (2 segments)
// ---------------------------------------------------------------------------
struct CSeg { const u16* x; const float* w; const float* b; u16* y; int C, nbx; };
struct CPack { CSeg s[2]; int start1; };

__global__ __launch_bounds__(256) void conv_pack_k(CPack pk) {
  const int bid = blockIdx.x;
  const int si = bid >= pk.start1;
  const CSeg q = pk.s[si];
  const int local = si ? bid - pk.start1 : bid;
  const int C = q.C;
  const int c = (local % q.nbx) * 64 + (threadIdx.x & 63);
  const int chunk = (local / q.nbx) * 4 + (threadIdx.x >> 6);
  const int T0 = chunk * 8;
  const float w0 = q.w[c * 4], w1 = q.w[c * 4 + 1], w2 = q.w[c * 4 + 2], w3 = q.w[c * 4 + 3];
  const float bs = q.b[c];
  const bool first = (T0 & (L - 1)) == 0;
  float v[11];
  #pragma unroll
  for (int i = 0; i < 11; ++i) {
    if (i < 3 && first) v[i] = 0.f;
    else v[i] = bf2f(q.x[(size_t)(T0 - 3 + i) * C + c]);
  }
  #pragma unroll
  for (int j = 0; j < 8; ++j) {
    float s = bs + w0 * v[j] + w1 * v[j + 1] + w2 * v[j + 2] + w3 * v[j + 3];
    q.y[(size_t)(T0 + j) * C + c] = f2bf(silu_f(s));
  }
}

// ---------------------------------------------------------------------------
// Packed MFMA bf16 GEMM (up to 4 segments). Tile 128x128, 4 waves, BK=32,
// 2-stage double-buffer, global_load_lds, per-segment XCD-bijective swizzle.
// ---------------------------------------------------------------------------
struct MSeg {
  const u16 *A0, *A1, *Wt;
  const float *bias, *res;
  float* outF; u16 *outB0, *outB1;
  int K, K1, Nout, ldA, ldo, split, nbx, nwg, epi;
};
struct MPack { MSeg s[4]; int starts[4]; int nseg; };

__global__ __launch_bounds__(256) void mfma_pack_k(MPack pk) {
  const int bid = blockIdx.x;
  int si = 0;
  #pragma unroll
  for (int k = 1; k < 4; ++k)
    if (k < pk.nseg && bid >= pk.starts[k]) si = k;
  const MSeg p = pk.s[si];
  const int wg = bid - pk.starts[si];

  __shared__ u16 As[2][4096];
  __shared__ u16 Bs[2][4096];
  const int tid = threadIdx.x;
  const int lane = tid & 63;
  const int wid = tid >> 6;
  const int wm = wid >> 1, wn = wid & 1;
  const int newid = (wg & 7) * (p.nwg >> 3) + (wg >> 3);
  const int n0 = (newid % p.nbx) * 128;
  const int m0 = (newid / p.nbx) * 128;
  const int srow = tid & 127;
  const int skc = tid >> 7;
  const int kgrp = lane >> 4, l16 = lane & 15;

  f32x4 acc[4][4];
  #pragma unroll
  for (int i = 0; i < 4; ++i)
    #pragma unroll
    for (int j = 0; j < 4; ++j)
      acc[i][j] = (f32x4){0.f, 0.f, 0.f, 0.f};

  auto stage = [&](int bi, int k0) {
    const u16* Ab = p.A0;
    int kc = k0;
    if (p.A1 && k0 >= p.K1) { Ab = p.A1; kc = k0 - p.K1; }
    const u16* g0 = Ab + (size_t)(m0 + srow) * p.ldA + kc + skc * 8;
    u16* Ad = &As[bi][0];
    __builtin_amdgcn_global_load_lds((const glb_u32*)g0,
        (lds_u32*)(Ad + wid * 512), 16, 0, 0);
    __builtin_amdgcn_global_load_lds((const glb_u32*)(g0 + 16),
        (lds_u32*)(Ad + 2048 + wid * 512), 16, 0, 0);
    const u16* h0 = p.Wt + (size_t)(n0 + srow) * p.K + k0 + skc * 8;
    u16* Bd = &Bs[bi][0];
    __builtin_amdgcn_global_load_lds((const glb_u32*)h0,
        (lds_u32*)(Bd + wid * 512), 16, 0, 0);
    __builtin_amdgcn_global_load_lds((const glb_u32*)(h0 + 16),
        (lds_u32*)(Bd + 2048 + wid * 512), 16, 0, 0);
  };

  const int nt = p.K >> 5;
  stage(0, 0);
  __syncthreads();
  for (int t = 0; t < nt; ++t) {
    const int cur = t & 1;
    if (t + 1 < nt) stage(cur ^ 1, (t + 1) << 5);
    s16x8 af[4], bfr[4];
    #pragma unroll
    for (int mi = 0; mi < 4; ++mi)
      af[mi] = *(const s16x8*)(&As[cur][0] + kgrp * 1024 + (wm * 64 + mi * 16 + l16) * 8);
    #pragma unroll
    for (int ni = 0; ni < 4; ++ni)
      bfr[ni] = *(const s16x8*)(&Bs[cur][0] + kgrp * 1024 + (wn * 64 + ni * 16 + l16) * 8);
    #pragma unroll
    for (int mi = 0; mi < 4; ++mi)
      #pragma unroll
      for (int ni = 0; ni < 4; ++ni)
        acc[mi][ni] = __builtin_amdgcn_mfma_f32_16x16x32_bf16(af[mi], bfr[ni], acc[mi][ni], 0, 0, 0);
    if (t + 1 < nt) __syncthreads();
  }

  if (p.epi == 2) {
    #pragma unroll
    for (int mi = 0; mi < 4; ++mi) {
      int token = m0 + wm * 64 + mi * 16 + (lane >> 4) * 4;
      int b = token >> 12, l = token & (L - 1);
      #pragma unroll
      for (int ni = 0; ni < 4; ++ni) {
        int n = n0 + wn * 64 + ni * 16 + l16;
        if (n < p.Nout) {
          size_t o = ((size_t)b * p.Nout + n) * L + l;
          float4 r = *(const float4*)(p.res + o);
          float4 v = make_float4(acc[mi][ni][0] + r.x, acc[mi][ni][1] + r.y,
                                 acc[mi][ni][2] + r.z, acc[mi][ni][3] + r.w);
          *(float4*)(p.outF + o) = v;
        }
      }
    }
  } else {
    #pragma unroll
    for (int mi = 0; mi < 4; ++mi) {
      #pragma unroll
      for (int j = 0; j < 4; ++j) {
        int token = m0 + wm * 64 + mi * 16 + (lane >> 4) * 4 + j;
        #pragma unroll
        for (int ni = 0; ni < 4; ++ni) {
          int n = n0 + wn * 64 + ni * 16 + l16;
          float v = acc[mi][ni][j];
          if (p.epi == 0) {
            if (n < p.Nout) p.outF[(size_t)token * p.ldo + n] = v;
          } else if (p.epi == 1) {
            if (n < p.Nout) p.outB0[(size_t)token * p.ldo + n] = f2bf(v);
          } else if (p.epi == 3) {
            if (n < p.Nout) p.outB0[(size_t)token * p.ldo + n] = f2bf(silu_f(v + p.bias[n]));
          } else if (p.epi == 4) {
            if (n < p.Nout) p.outB0[(size_t)token * p.ldo + n] = f2bf(v + p.bias[n]);
          } else {  // 5: split
            if (n < p.split) p.outB0[(size_t)token * p.split + n] = f2bf(v);
            else p.outB1[(size_t)token * p.split + (n - p.split)] = f2bf(v);
          }
        }
      }
    }
  }
}

// ---------------------------------------------------------------------------
// Packed small fp32 GEMM (dt projections): softplus(x + eb[n]) epilogue
// ---------------------------------------------------------------------------
struct FSeg { const float* A0; const float* W; const float* eb; float* out; int K, N, lda, ldo, nbx; };
struct FPack { FSeg s[2]; int start1; };

__global__ __launch_bounds__(256) void gemm_f32_pack_k(FPack pk) {
  const int bid = blockIdx.x;
  const int si = bid >= pk.start1;
  const FSeg p = pk.s[si];
  const int local = si ? bid - pk.start1 : bid;
  const int n0 = (local % p.nbx) * 64;
  const int m0 = (local / p.nbx) * 64;

  __shared__ __align__(16) float As[16][64];
  __shared__ __align__(16) float Bs[16][64];
  const int tid = threadIdx.x;
  const int kidx = tid >> 4;
  const int li4 = (tid & 15) << 2;
  const int r0 = (tid & 15) << 2;
  const int c0 = (tid >> 4) << 2;
  float acc[4][4] = {};

  for (int k0 = 0; k0 < p.K; k0 += 16) {
    __syncthreads();
    {
      const int row = tid >> 2;
      const int kk4 = (tid & 3) << 2;
      const float* src = p.A0 + (size_t)(m0 + row) * p.lda;
      #pragma unroll
      for (int j = 0; j < 4; ++j) {
        int k = k0 + kk4 + j;
        As[kk4 + j][row] = (k < p.K) ? src[k] : 0.f;
      }
    }
    {
      int k = k0 + kidx;
      #pragma unroll
      for (int j = 0; j < 4; ++j) {
        int n = n0 + li4 + j;
        Bs[kidx][li4 + j] = (k < p.K && n < p.N) ? p.W[(size_t)k * p.N + n] : 0.f;
      }
    }
    __syncthreads();
    #pragma unroll
    for (int kk = 0; kk < 16; ++kk) {
      float4 a = *(const float4*)&As[kk][r0];
      float4 bq = *(const float4*)&Bs[kk][c0];
      float av[4] = {a.x, a.y, a.z, a.w};
      float bv[4] = {bq.x, bq.y, bq.z, bq.w};
      #pragma unroll
      for (int i = 0; i < 4; ++i)
        #pragma unroll
        for (int j = 0; j < 4; ++j)
          acc[i][j] = fmaf(av[i], bv[j], acc[i][j]);
    }
  }
  float eb[4] = {p.eb[n0 + c0], p.eb[n0 + c0 + 1], p.eb[n0 + c0 + 2], p.eb[n0 + c0 + 3]};
  #pragma unroll
  for (int i = 0; i < 4; ++i) {
    float4 v;
    v.x = softplus_f(acc[i][0] + eb[0]);
    v.y = softplus_f(acc[i][1] + eb[1]);
    v.z = softplus_f(acc[i][2] + eb[2]);
    v.w = softplus_f(acc[i][3] + eb[3]);
    *(float4*)&p.out[(size_t)(m0 + r0 + i) * p.ldo + n0 + c0] = v;
  }
}

// ---------------------------------------------------------------------------
// Packed chunked selective scan v2: 256-thread blocks, 2 channels per thread.
// Fast path (runtime-verified): An[n] == (n+1)*An[0]  =>  exp(dl*An[n]) = a^(n+1)
// with a = exp(dl*An[0]) — 1 exp + 15 muls instead of 16 exps per channel-token.
// Generic slow path kept for arbitrary A.
// PF layout [c][slot 0..31][NCH]: slots 0..15 = P, 16..31 = F/Hin.
// P computed as exp(An * sum(dl)) once per chunk.
// ---------------------------------------------------------------------------
struct S2Seg {
  const u16* u; const float* dlt; const float* Alog; const float* xdbl;
  const float* Dp; const u16* zT; float* PF; u16* yT;
  int roff, Dch, CLen, NCH;
};
struct S2Pack { S2Seg s[2]; int start1; };

template<int PASS>
__global__ __launch_bounds__(256) void scan2_pack_k(S2Pack pk) {
  const int bid = blockIdx.x;
  const int si = bid >= pk.start1;
  const S2Seg q = pk.s[si];
  const int lbid = si ? bid - pk.start1 : bid;
  const int gtid = lbid * 256 + (int)threadIdx.x;
  const int Dch = q.Dch;
  const int npair = Dch >> 1;
  const int NC = L / q.CLen;
  const int dpi = gtid % npair;
  const int c = (gtid / npair) % NC;
  const int b = gtid / (npair * NC);
  const int d0 = dpi * 2;
  const size_t tok0 = (size_t)b * L + (size_t)c * q.CLen;

  float An[2][16], h[2][16];
  #pragma unroll
  for (int j = 0; j < 2; ++j)
    #pragma unroll
    for (int n = 0; n < 16; ++n) {
      An[j][n] = -__expf(q.Alog[(d0 + j) * 16 + n]);
      h[j][n] = 0.f;
    }
  // fast-path check: An[n] == (n+1) * An[0] (relative tol)
  bool fast = true;
  #pragma unroll
  for (int j = 0; j < 2; ++j)
    #pragma unroll
    for (int n = 1; n < 16; ++n) {
      float ref = (float)(n + 1) * An[j][0];
      if (fabsf(An[j][n] - ref) > 1e-4f * fabsf(ref)) fast = false;
    }

  const int ch0 = b * Dch + d0;
  if (PASS == 3) {
    #pragma unroll
    for (int j = 0; j < 2; ++j)
      #pragma unroll
      for (int n = 0; n < 16; ++n)
        h[j][n] = q.PF[((size_t)c * 32 + 16 + n) * q.NCH + ch0 + j];
  }
  const float Dd0 = q.Dp[d0], Dd1 = q.Dp[d0 + 1];
  const u16* up = q.u + tok0 * Dch + d0;
  const float* dp = q.dlt + tok0 * Dch + d0;
  const u16* zp = q.zT + tok0 * Dch + d0;
  u16* yr = q.yT + tok0 * Dch + d0;
  const float* xr = q.xdbl + tok0 * 64 + q.roff;
  float S0 = 0.f, S1 = 0.f;

  #define SCAN_BODY(FAST)                                                      \
  for (int t = 0; t < q.CLen; ++t) {                                           \
    const size_t od = (size_t)t * Dch;                                         \
    float2 dl2 = *(const float2*)(dp + od);                                    \
    u32 uu2 = *(const u32*)(up + od);                                          \
    float u0 = bf2f((u16)uu2), u1 = bf2f((u16)(uu2 >> 16));                    \
    float w0 = dl2.x * u0, w1 = dl2.y * u1;                                    \
    const float2* bp = (const float2*)(xr + (size_t)t * 64);                   \
    float Bv[16];                                                              \
    _Pragma("unroll")                                                          \
    for (int qq = 0; qq < 8; ++qq) {                                           \
      float2 bv = bp[qq]; Bv[2 * qq] = bv.x; Bv[2 * qq + 1] = bv.y;            \
    }                                                                          \
    if (PASS == 1) { S0 += dl2.x; S1 += dl2.y; }                               \
    float y0 = 0.f, y1 = 0.f;                                                  \
    if (FAST) {                                                                \
      float a0 = __expf(dl2.x * An[0][0]);                                     \
      float a1 = __expf(dl2.y * An[1][0]);                                     \
      float e0 = a0, e1 = a1;                                                  \
      h[0][0] = fmaf(e0, h[0][0], w0 * Bv[0]);                                 \
      h[1][0] = fmaf(e1, h[1][0], w1 * Bv[0]);                                 \
      _Pragma("unroll")                                                        \
      for (int n = 1; n < 16; ++n) {                                           \
        e0 *= a0; e1 *= a1;                                                    \
        h[0][n] = fmaf(e0, h[0][n], w0 * Bv[n]);                               \
        h[1][n] = fmaf(e1, h[1][n], w1 * Bv[n]);                               \
      }                                                                        \
    } else {                                                                   \
      _Pragma("unroll")                                                        \
      for (int n = 0; n < 16; ++n) {                                           \
        h[0][n] = fmaf(__expf(dl2.x * An[0][n]), h[0][n], w0 * Bv[n]);         \
        h[1][n] = fmaf(__expf(dl2.y * An[1][n]), h[1][n], w1 * Bv[n]);         \
      }                                                                        \
    }                                                                          \
    if (PASS == 3) {                                                           \
      _Pragma("unroll")                                                        \
      for (int qq = 0; qq < 8; ++qq) {                                         \
        float2 cv = bp[qq + 8];                                                \
        y0 = fmaf(h[0][2 * qq], cv.x, y0); y0 = fmaf(h[0][2 * qq + 1], cv.y, y0); \
        y1 = fmaf(h[1][2 * qq], cv.x, y1); y1 = fmaf(h[1][2 * qq + 1], cv.y, y1); \
      }                                                                        \
      u32 zz2 = *(const u32*)(zp + od);                                        \
      float z0 = bf2f((u16)zz2), z1 = bf2f((u16)(zz2 >> 16));                  \
      y0 = (y0 + Dd0 * u0) * silu_f(z0);                                       \
      y1 = (y1 + Dd1 * u1) * silu_f(z1);                                       \
      u32 out = (u32)f2bf(y0) | ((u32)f2bf(y1) << 16);                         \
      *(u32*)(yr + od) = out;                                                  \
    }                                                                          \
  }

  if (fast) { SCAN_BODY(1) } else { SCAN_BODY(0) }
  #undef SCAN_BODY

  if (PASS == 1) {
    #pragma unroll
    for (int n = 0; n < 16; ++n) {
      q.PF[((size_t)c * 32 + n) * q.NCH + ch0]     = __expf(An[0][n] * S0);
      q.PF[((size_t)c * 32 + n) * q.NCH + ch0 + 1] = __expf(An[1][n] * S1);
      q.PF[((size_t)c * 32 + 16 + n) * q.NCH + ch0]     = h[0][n];
      q.PF[((size_t)c * 32 + 16 + n) * q.NCH + ch0 + 1] = h[1][n];
    }
  }
}

// Packed stitch: per (ch, state) sequential over chunks; rewrites F with Hin.
__global__ __launch_bounds__(256) void stitch_pack_k(
    float* PF0, int NC0, int NCH0, int tot0,
    float* PF1, int NC1, int NCH1, int tot1) {
  int idx = blockIdx.x * 256 + threadIdx.x;
  float* PF; int NC, NCH;
  if (idx < tot0) { PF = PF0; NC = NC0; NCH = NCH0; }
  else { idx -= tot0; if (idx >= tot1) return; PF = PF1; NC = NC1; NCH = NCH1; }
  int ch = idx % NCH, n = idx / NCH;
  float hin = 0.f;
  for (int c = 0; c < NC; ++c) {
    float* Ps = PF + ((size_t)c * 32 + n) * NCH + ch;
    float* Fs = PF + ((size_t)c * 32 + 16 + n) * NCH + ch;
    float Pv = *Ps, Fv = *Fs;
    *Fs = hin;
    hin = fmaf(Pv, hin, Fv);
  }
}

// ---------------------------------------------------------------------------
extern "C" void kernel_launch(void* const* d_in, const int* in_sizes, int n_in,
                              void* d_out, int out_size, void* d_ws, size_t ws_size,
                              hipStream_t stream) {
  const float* m_ll    = (const float*)d_in[0];
  const float* m_high  = (const float*)d_in[1];
  const float* zanc    = (const float*)d_in[2];
  const float* Kin     = (const float*)d_in[3];
  const float* Qin     = (const float*)d_in[4];
  const float* s_in_w  = (const float*)d_in[5];
  const float* s_conv_w= (const float*)d_in[6];
  const float* s_conv_b= (const float*)d_in[7];
  const float* s_x_w   = (const float*)d_in[8];
  const float* s_dt_w  = (const float*)d_in[9];
  const float* s_dt_b  = (const float*)d_in[10];
  const float* s_Alog  = (const float*)d_in[11];
  const float* s_D     = (const float*)d_in[12];
  const float* s_out_w = (const float*)d_in[13];
  const float* t_in_w  = (const float*)d_in[14];
  const float* t_conv_w= (const float*)d_in[15];
  const float* t_conv_b= (const float*)d_in[16];
  const float* t_kln_g = (const float*)d_in[17];
  const float* t_kln_b = (const float*)d_in[18];
  const float* t_k_w   = (const float*)d_in[19];
  const float* t_k_b   = (const float*)d_in[20];
  const float* t_qln_g = (const float*)d_in[21];
  const float* t_qln_b = (const float*)d_in[22];
  const float* t_q_w   = (const float*)d_in[23];
  const float* t_q_b   = (const float*)d_in[24];
  const float* t_dtbc_w= (const float*)d_in[25];
  const float* t_dt_w  = (const float*)d_in[26];
  const float* t_dt_b  = (const float*)d_in[27];
  const float* t_gate_w= (const float*)d_in[28];
  const float* t_gate_b= (const float*)d_in[29];
  const float* t_Alog  = (const float*)d_in[30];
  const float* t_D     = (const float*)d_in[31];
  const float* t_out_w = (const float*)d_in[32];

  float* out1 = (float*)d_out;               // (4, 96, 4096)
  float* out2 = out1 + (size_t)4 * 96 * L;   // (4, 288, 4096) = 4,718,592 f
  float* ws = (float*)d_ws;

  // Weights (bf16)
  u16* w_sin   = (u16*)(ws + 0);        // [384][96]
  u16* w_sx    = (u16*)(ws + 18432);    // [128][192]
  u16* w_sout  = (u16*)(ws + 30720);    // [128][192]
  u16* w_tin   = (u16*)(ws + 43008);    // [640][288]
  u16* w_tk    = (u16*)(ws + 135168);   // [640][288]
  u16* w_tq    = (u16*)(ws + 227328);   // [640][288]
  u16* w_tdtbc = (u16*)(ws + 319488);   // [128][1152]
  u16* w_tgate = (u16*)(ws + 393216);   // [640][1152]
  u16* w_tout  = (u16*)(ws + 761856);   // [384][576]

  // Activations (float offsets; both streams live simultaneously)
  float* B_ahi  = ws + 872448;    // a_hi  u16[16384][288]
  float* B_aK   = ws + 2052096;
  float* B_aQ   = ws + 3231744;
  float* B_all  = ws + 4411392;   // a_ll u16[16384][96]
  float* B_xin  = ws + 5197824;   // x_in u16[16384][192]
  float* B_zTs  = ws + 6770688;
  float* B_xc   = ws + 8343552;
  float* B_xin3 = ws + 9916416;   // xin3 u16[16384][576]
  float* B_xc3  = ws + 14635008;
  float* B_kp   = ws + 19353600;
  float* B_qp   = ws + 24072192;
  float* B_zg3  = ws + 28790784;
  float* B_xdbl = ws + 33509376;  // fp32 [16384][64]
  float* B_xdbl3= ws + 34557952;  // fp32 [16384][64]
  float* B_PFs  = ws + 35606528;  // fp32 128*32*768
  // Overlays (liveness-checked):
  float* B_dlt  = B_ahi;          // fp32 [16384][192] over a_hi..aQ (dead after P1)
  float* B_dlt3 = B_kp;           // fp32 [16384][576] over kp+qp (dead after P2)
  u16* y_bf = (u16*)B_xin;        // over x_in (dead after conv)
  u16* y3   = (u16*)B_xin3;       // over xin3 (dead after conv)
  float* PFt = out2;              // 64*32*2304 == |out2| (dead until P3)

  dim3 blk(256);

  // 1) weight conversion
  {
    WAll wa;
    wa.s[0] = {s_in_w,   w_sin,    96, 384, 384};
    wa.s[1] = {s_x_w,    w_sx,    192,  38, 128};
    wa.s[2] = {s_out_w,  w_sout,  192,  96, 128};
    wa.s[3] = {t_in_w,   w_tin,   288, 576, 640};
    wa.s[4] = {t_k_w,    w_tk,    288, 576, 640};
    wa.s[5] = {t_q_w,    w_tq,    288, 576, 640};
    wa.s[6] = {t_dtbc_w, w_tdtbc, 1152, 50, 128};
    wa.s[7] = {t_gate_w, w_tgate, 1152, 576, 640};
    wa.s[8] = {t_out_w,  w_tout,  576, 288, 384};
    wconv_k<<<dim3(20, 36, 9), blk, 0, stream>>>(wa);
  }

  // 2) all four transpose-preps (4 x 512 blocks)
  {
    TPack tp{};
    tp.s[0] = {m_ll,   nullptr, nullptr, zanc,    (u16*)B_all, 96,  0};
    tp.s[1] = {m_high, nullptr, nullptr, nullptr, (u16*)B_ahi, 288, 0};
    tp.s[2] = {Kin,    t_kln_g, t_kln_b, nullptr, (u16*)B_aK,  288, 1};
    tp.s[3] = {Qin,    t_qln_g, t_qln_b, nullptr, (u16*)B_aQ,  288, 1};
    trans_pack_k<<<dim3(2048), blk, 0, stream>>>(tp);
  }

  // 3) P1: s_in + t_in + t_k + t_q (2304 blocks)
  {
    MPack pk{}; pk.nseg = 4;
    pk.starts[0] = 0; pk.starts[1] = 384; pk.starts[2] = 1024; pk.starts[3] = 1664;
    MSeg a{}; a.A0 = (u16*)B_all; a.Wt = w_sin; a.K = 96; a.K1 = 1 << 28; a.Nout = 384;
    a.ldA = 96; a.split = 192; a.outB0 = (u16*)B_xin; a.outB1 = (u16*)B_zTs;
    a.nbx = 3; a.nwg = 384; a.epi = 5; pk.s[0] = a;
    MSeg b{}; b.A0 = (u16*)B_ahi; b.Wt = w_tin; b.K = 288; b.K1 = 1 << 28; b.Nout = 576;
    b.ldA = 288; b.ldo = 576; b.outB0 = (u16*)B_xin3; b.nbx = 5; b.nwg = 640; b.epi = 1; pk.s[1] = b;
    MSeg c{}; c.A0 = (u16*)B_aK; c.Wt = w_tk; c.K = 288; c.K1 = 1 << 28; c.Nout = 576;
    c.ldA = 288; c.ldo = 576; c.bias = t_k_b; c.outB0 = (u16*)B_kp; c.nbx = 5; c.nwg = 640; c.epi = 3; pk.s[2] = c;
    MSeg d{}; d.A0 = (u16*)B_aQ; d.Wt = w_tq; d.K = 288; d.K1 = 1 << 28; d.Nout = 576;
    d.ldA = 288; d.ldo = 576; d.bias = t_q_b; d.outB0 = (u16*)B_qp; d.nbx = 5; d.nwg = 640; d.epi = 3; pk.s[3] = d;
    mfma_pack_k<<<dim3(2304), blk, 0, stream>>>(pk);
  }

  // 4) both convs (1536 + 4608 blocks)
  {
    CPack cp{}; cp.start1 = 1536;
    cp.s[0] = {(u16*)B_xin,  s_conv_w, s_conv_b, (u16*)B_xc,  192, 3};
    cp.s[1] = {(u16*)B_xin3, t_conv_w, t_conv_b, (u16*)B_xc3, 576, 9};
    conv_pack_k<<<dim3(6144), blk, 0, stream>>>(cp);
  }

  // 5) P2: s_x + dtbc + gate (896 blocks)
  {
    MPack pk{}; pk.nseg = 3;
    pk.starts[0] = 0; pk.starts[1] = 128; pk.starts[2] = 256; pk.starts[3] = 896;
    MSeg a{}; a.A0 = (u16*)B_xc; a.Wt = w_sx; a.K = 192; a.K1 = 1 << 28; a.Nout = 64;
    a.ldA = 192; a.ldo = 64; a.outF = B_xdbl; a.nbx = 1; a.nwg = 128; a.epi = 0; pk.s[0] = a;
    MSeg b{}; b.A0 = (u16*)B_xc3; b.A1 = (u16*)B_kp; b.Wt = w_tdtbc; b.K = 1152; b.K1 = 576;
    b.Nout = 64; b.ldA = 576; b.ldo = 64; b.outF = B_xdbl3; b.nbx = 1; b.nwg = 128; b.epi = 0; pk.s[1] = b;
    MSeg c{}; c.A0 = (u16*)B_xc3; c.A1 = (u16*)B_qp; c.Wt = w_tgate; c.K = 1152; c.K1 = 576;
    c.Nout = 576; c.ldA = 576; c.ldo = 576; c.bias = t_gate_b; c.outB0 = (u16*)B_zg3;
    c.nbx = 5; c.nwg = 640; c.epi = 4; pk.s[2] = c;
    mfma_pack_k<<<dim3(896), blk, 0, stream>>>(pk);
  }

  // 6) both dt-projection fp32 GEMMs
  {
    FPack fp{}; fp.start1 = 768;
    fp.s[0] = {B_xdbl,  s_dt_w, s_dt_b, B_dlt,  6,  192, 64, 192, 3};
    fp.s[1] = {B_xdbl3, t_dt_w, t_dt_b, B_dlt3, 18, 576, 64, 576, 9};
    gemm_f32_pack_k<<<dim3(3072), blk, 0, stream>>>(fp);
  }

  // 7-9) scans (2ch/thread, 256-thread blocks) + stitch
  // SSS: 96 pairs * 128 chunks * 4 b = 49152 threads = 192 blocks
  // STS: 288 pairs * 64 chunks * 4 b = 73728 threads = 288 blocks
  S2Pack sp{}; sp.start1 = 192;
  sp.s[0] = {(u16*)B_xc,  B_dlt,  s_Alog, B_xdbl,  s_D, (u16*)B_zTs, B_PFs, y_bf, 6,  192, 32, 768};
  sp.s[1] = {(u16*)B_xc3, B_dlt3, t_Alog, B_xdbl3, t_D, (u16*)B_zg3, PFt,   y3,   18, 576, 64, 2304};
  scan2_pack_k<1><<<dim3(480), blk, 0, stream>>>(sp);
  stitch_pack_k<<<dim3(192), blk, 0, stream>>>(B_PFs, 128, 768, 12288, PFt, 64, 2304, 36864);
  scan2_pack_k<3><<<dim3(480), blk, 0, stream>>>(sp);

  // 10) P3: s_out + t_out (512 blocks)
  {
    MPack pk{}; pk.nseg = 2;
    pk.starts[0] = 0; pk.starts[1] = 128; pk.starts[2] = 512; pk.starts[3] = 512;
    MSeg a{}; a.A0 = y_bf; a.Wt = w_sout; a.K = 192; a.K1 = 1 << 28; a.Nout = 96;
    a.ldA = 192; a.res = m_ll; a.outF = out1; a.nbx = 1; a.nwg = 128; a.epi = 2; pk.s[0] = a;
    MSeg b{}; b.A0 = y3; b.Wt = w_tout; b.K = 576; b.K1 = 1 << 28; b.Nout = 288;
    b.ldA = 576; b.res = m_high; b.outF = out2; b.nbx = 3; b.nwg = 384; b.epi = 2; pk.s[1] = b;
    mfma_pack_k<<<dim3(512), blk, 0, stream>>>(pk);
  }
}